// Round 4
// baseline (53.133 us; speedup 1.0000x reference)
//
#include <hip/hip_runtime.h>
#include <hip/hip_bf16.h>

#define CIN   64
#define COUT  128
#define TT    256
#define VV    25
#define TV    (TT * VV)   // 6400
#define KW    9
#define PAD   4
#define RSF   32          // attn LDS row stride (floats) = 128 B, XOR-swizzled

typedef __attribute__((ext_vector_type(8))) short short8;   // 8 bf16 (4 VGPRs)
typedef __attribute__((ext_vector_type(4))) float f32x4;

__device__ __forceinline__ unsigned f2b(float f) {          // fp32 -> bf16 bits (RNE)
    unsigned u = __builtin_bit_cast(unsigned, f);
    return (u + 0x7FFFu + ((u >> 16) & 1u)) >> 16;
}
__device__ __forceinline__ float b2f(unsigned short u) {    // bf16 bits -> fp32 (exact)
    unsigned v = (unsigned)u << 16;
    return __builtin_bit_cast(float, v);
}
// conv LDS tile swizzle: [row][128B], XOR slot with (row&7) (lane row-stride 1)
__device__ __forceinline__ int swz(int row, int cbyte) {
    return row * 128 + ((cbyte & ~15) ^ ((row & 7) << 4)) + (cbyte & 15);
}
// attn LDS float index: lane row-stride is 2 (t0 = 2*tid), so XOR with (row>>1)&7
__device__ __forceinline__ int aswz(int t, int v) {
    return t * RSF + ((((v >> 2) ^ ((t >> 1) & 7))) << 2) + (v & 3);
}
__device__ __forceinline__ const float4* arow(const float* yl, int r, int k) {
    return (const float4*)&yl[r * RSF + ((k ^ ((r >> 1) & 7)) << 2)];
}

// ---------------- Kernel A: 1x1 conv + BN via bf16 MFMA ----------------
// grid (50 pos-chunks, 16 n); block 256 = 4 waves.
__global__ __launch_bounds__(256) void conv_mfma(
    const float* __restrict__ x, const float* __restrict__ w,
    const float* __restrict__ cb, const float* __restrict__ gamma,
    const float* __restrict__ beta, const float* __restrict__ rm,
    const float* __restrict__ rv, unsigned short* __restrict__ y)
{
    __shared__ __align__(16) unsigned short Wl[COUT * 64];   // 16 KB, swizzled
    __shared__ __align__(16) unsigned short Xl[128 * 64];    // 16 KB, swizzled [pos][c]
    __shared__ float sc[COUT];
    __shared__ float of[COUT];

    const int pc  = blockIdx.x;       // 0..49
    const int n   = blockIdx.y;       // 0..15
    const int tid = threadIdx.x;
    const int posbase = pc * 128;

    if (tid < COUT) {
        const float s = gamma[tid] * rsqrtf(rv[tid] + 1e-5f);
        sc[tid] = s;
        of[tid] = cb[tid] * s + beta[tid] - rm[tid] * s;
    }
    for (int idx = tid; idx < 2048; idx += 256) {
        const int c4 = idx & 15, o = idx >> 4;
        const f32x4 wv = *(const f32x4*)(w + o * 64 + c4 * 4);
        uint2 pk;
        pk.x = f2b(wv.x) | (f2b(wv.y) << 16);
        pk.y = f2b(wv.z) | (f2b(wv.w) << 16);
        *(uint2*)((char*)Wl + swz(o, c4 * 8)) = pk;
    }
    for (int idx = tid; idx < 2048; idx += 256) {
        const int pos = idx & 127, c4 = idx >> 7;
        const float* xp = x + (size_t)n * CIN * TV + (size_t)(c4 * 4) * TV + posbase + pos;
        const float a0 = xp[0], a1 = xp[TV], a2 = xp[2 * TV], a3 = xp[3 * TV];
        uint2 pk;
        pk.x = f2b(a0) | (f2b(a1) << 16);
        pk.y = f2b(a2) | (f2b(a3) << 16);
        *(uint2*)((char*)Xl + swz(pos, c4 * 8)) = pk;
    }
    __syncthreads();

    const int wv_ = tid >> 6, lane = tid & 63;
    const int lr = lane & 15, lh = lane >> 4;   // lh in 0..3

    short8 afr[2][2];
#pragma unroll
    for (int m0 = 0; m0 < 2; ++m0)
#pragma unroll
        for (int kh = 0; kh < 2; ++kh)
            afr[m0][kh] = *(const short8*)((const char*)Wl +
                              swz(wv_ * 32 + m0 * 16 + lr, kh * 64 + lh * 16));

    f32x4 acc[2][8];
#pragma unroll
    for (int m0 = 0; m0 < 2; ++m0)
#pragma unroll
        for (int n0 = 0; n0 < 8; ++n0) acc[m0][n0] = (f32x4){0.f, 0.f, 0.f, 0.f};

#pragma unroll
    for (int n0 = 0; n0 < 8; ++n0) {
        const int prow = n0 * 16 + lr;
        const short8 b0 = *(const short8*)((const char*)Xl + swz(prow, lh * 16));
        const short8 b1 = *(const short8*)((const char*)Xl + swz(prow, 64 + lh * 16));
#pragma unroll
        for (int m0 = 0; m0 < 2; ++m0) {
            acc[m0][n0] = __builtin_amdgcn_mfma_f32_16x16x32_bf16(afr[m0][0], b0, acc[m0][n0], 0, 0, 0);
            acc[m0][n0] = __builtin_amdgcn_mfma_f32_16x16x32_bf16(afr[m0][1], b1, acc[m0][n0], 0, 0, 0);
        }
    }

    unsigned short* yb = y + (size_t)n * COUT * TV + posbase;
#pragma unroll
    for (int m0 = 0; m0 < 2; ++m0)
#pragma unroll
        for (int n0 = 0; n0 < 8; ++n0)
#pragma unroll
            for (int r = 0; r < 4; ++r) {
                const int o = wv_ * 32 + m0 * 16 + lh * 4 + r;
                const int pos = n0 * 16 + lr;
                const float val = acc[m0][n0][r] * sc[o] + of[o];
                yb[(size_t)o * TV + pos] = (unsigned short)f2b(val);
            }
}

// ---------------- Kernel B: temporal-window attention (bf16 y in) ----------------
// 2048 blocks x 128 threads; thread handles t0=2*tid, t1=t0+1.
// LDS rows 128 B, slot XOR-swizzled on (row>>1)&7 -> conflict-free ds_read_b128
// for the stride-2 lane->row pattern.
__global__ __launch_bounds__(128) void attn_kernel(
    const unsigned short* __restrict__ y, const float* __restrict__ att0,
    float* __restrict__ out)
{
    __shared__ float yl[TT * RSF];    // 32 KB
    __shared__ float a0s[KW];

    const int nc  = blockIdx.x;       // n*COUT + c
    const int c   = nc & (COUT - 1);
    const int tid = threadIdx.x;

    const unsigned short* yp = y + (size_t)nc * TV;

    // zero pad elements v=25..31 of each row (read by the XOR'd slot sweep)
    for (int j = tid; j < TT * 7; j += 128) {
        const int t = j / 7, p = j - t * 7;
        yl[aswz(t, 25 + p)] = 0.f;
    }
    // stage y (bf16 -> fp32), swizzled scatter
    for (int i = tid; i < TV / 4; i += 128) {
        const ushort4 u = *(const ushort4*)(yp + i * 4);
        const int e = i * 4;
        const float f[4] = { b2f(u.x), b2f(u.y), b2f(u.z), b2f(u.w) };
#pragma unroll
        for (int j = 0; j < 4; ++j) {
            const int t = (e + j) / 25, v = (e + j) % 25;
            yl[aswz(t, v)] = f[j];
        }
    }
    if (tid < KW) a0s[tid] = att0[c * KW + tid];
    __syncthreads();

    const int t0 = tid * 2, t1 = t0 + 1;

    float4 yc0[7], yc1[7];
#pragma unroll
    for (int k = 0; k < 7; ++k) { yc0[k] = *arow(yl, t0, k); yc1[k] = *arow(yl, t1, k); }

    // ---- scores ----
    float s0[KW], s1[KW];
#pragma unroll
    for (int u = 0; u < KW; ++u) { s0[u] = 0.f; s1[u] = 0.f; }

#pragma unroll
    for (int j = 0; j < 10; ++j) {
        const int r = t0 - PAD + j;
        if (r >= 0 && r < TT) {
            float d0 = 0.f, d1 = 0.f;
#pragma unroll
            for (int k = 0; k < 7; ++k) {
                const float4 q = *arow(yl, r, k);
                d0 = fmaf(q.x, yc0[k].x, d0); d0 = fmaf(q.y, yc0[k].y, d0);
                d0 = fmaf(q.z, yc0[k].z, d0); d0 = fmaf(q.w, yc0[k].w, d0);
                d1 = fmaf(q.x, yc1[k].x, d1); d1 = fmaf(q.y, yc1[k].y, d1);
                d1 = fmaf(q.z, yc1[k].z, d1); d1 = fmaf(q.w, yc1[k].w, d1);
            }
            if (j <= 8) s0[j]     = d0 * (1.f / (float)VV);
            if (j >= 1) s1[j - 1] = d1 * (1.f / (float)VV);
        }
    }

    // ---- softmax + att0 ----
    float aw0[KW], aw1[KW];
    {
        float m0 = s0[0], m1 = s1[0];
#pragma unroll
        for (int u = 1; u < KW; ++u) { m0 = fmaxf(m0, s0[u]); m1 = fmaxf(m1, s1[u]); }
        float d0 = 0.f, d1 = 0.f;
#pragma unroll
        for (int u = 0; u < KW; ++u) {
            aw0[u] = __expf(s0[u] - m0); d0 += aw0[u];
            aw1[u] = __expf(s1[u] - m1); d1 += aw1[u];
        }
        const float i0 = 1.f / d0, i1 = 1.f / d1;
#pragma unroll
        for (int u = 0; u < KW; ++u) {
            aw0[u] = aw0[u] * i0 + a0s[u];
            aw1[u] = aw1[u] * i1 + a0s[u];
        }
    }

    // ---- PV ----
    float4 o0[7], o1[7];
#pragma unroll
    for (int k = 0; k < 7; ++k) {
        o0[k] = make_float4(0.f, 0.f, 0.f, 0.f);
        o1[k] = make_float4(0.f, 0.f, 0.f, 0.f);
    }
#pragma unroll
    for (int j = 0; j < 10; ++j) {
        const int r = t0 - PAD + j;
        if (r >= 0 && r < TT) {
#pragma unroll
            for (int k = 0; k < 7; ++k) {
                const float4 q = *arow(yl, r, k);
                if (j <= 8) {
                    const float a = aw0[j];
                    o0[k].x = fmaf(a, q.x, o0[k].x); o0[k].y = fmaf(a, q.y, o0[k].y);
                    o0[k].z = fmaf(a, q.z, o0[k].z); o0[k].w = fmaf(a, q.w, o0[k].w);
                }
                if (j >= 1) {
                    const float a = aw1[j - 1];
                    o1[k].x = fmaf(a, q.x, o1[k].x); o1[k].y = fmaf(a, q.y, o1[k].y);
                    o1[k].z = fmaf(a, q.z, o1[k].z); o1[k].w = fmaf(a, q.w, o1[k].w);
                }
            }
        }
    }

    // ---- overlay packed fp32 output in LDS, then coalesced float4 stores ----
    __syncthreads();
    {
        float* op0 = &yl[t0 * VV];
        float* op1 = &yl[t1 * VV];
#pragma unroll
        for (int k = 0; k < 6; ++k) {
            op0[4*k+0] = o0[k].x; op0[4*k+1] = o0[k].y; op0[4*k+2] = o0[k].z; op0[4*k+3] = o0[k].w;
            op1[4*k+0] = o1[k].x; op1[4*k+1] = o1[k].y; op1[4*k+2] = o1[k].z; op1[4*k+3] = o1[k].w;
        }
        op0[24] = o0[6].x;
        op1[24] = o1[6].x;
    }
    __syncthreads();
    {
        float4* og = (float4*)(out + (size_t)nc * TV);
        const float4* yl4 = (const float4*)yl;
        for (int i = tid; i < TV / 4; i += 128) og[i] = yl4[i];
    }
}

extern "C" void kernel_launch(void* const* d_in, const int* in_sizes, int n_in,
                              void* d_out, int out_size, void* d_ws, size_t ws_size,
                              hipStream_t stream)
{
    const float* x     = (const float*)d_in[0];
    const float* w     = (const float*)d_in[1];
    const float* cb    = (const float*)d_in[2];
    const float* gamma = (const float*)d_in[3];
    const float* beta  = (const float*)d_in[4];
    const float* rm    = (const float*)d_in[5];
    const float* rv    = (const float*)d_in[6];
    const float* att0  = (const float*)d_in[7];
    float* out = (float*)d_out;
    unsigned short* y = (unsigned short*)d_ws;   // 26.2 MB bf16 scratch

    dim3 gA(TV / 128, 16);   // 50 x 16
    conv_mfma<<<gA, 256, 0, stream>>>(x, w, cb, gamma, beta, rm, rv, y);

    dim3 gB(16 * COUT);
    attn_kernel<<<gB, 128, 0, stream>>>(y, att0, out);
}